// Round 11
// baseline (137.543 us; speedup 1.0000x reference)
//
#include <hip/hip_runtime.h>
#include <hip/hip_cooperative_groups.h>
#include <math.h>

namespace cg = cooperative_groups;

#define N_NODES 12288
#define N_EDGES 393216
#define EPS 1e-8f

#define NB 1024            // blocks; all co-resident (4/CU x 256 CU)
#define NPB 12             // nodes per bin: 12288/1024
#define NXCD 8
#define NSUB (NB * NXCD)   // 8192 sub-bins
#define CAP_SUB 256        // records per sub-bin; mean 96, ~16 sigma headroom
#define NSLOT 128          // per-node CSR capacity; unique deg ~Poisson(64), 8 sigma
#define BMW 384            // bitmap words per node: 12288/32
#define SM_FLOATS (2 * 64 * 65)   // 8320 floats = 33280 B (union high-water)

__device__ __forceinline__ float wave_sum(float v) {
    #pragma unroll
    for (int off = 32; off; off >>= 1) v += __shfl_xor(v, off);
    return v;
}

// ---------------- fused cooperative kernel ----------------
// Per block: stage W -> edge-bin (grid-stride, 12 iters/wave) -> phase1
// (3 nodes/wave) -> grid.sync -> bin-gather + projective chain.
// LDS union: W[8320 floats] before the grid barrier; csr(12288B)+bm(18432B)
// +cnt(48B) after. Safe: phase1 reads W strictly before grid.sync; gather
// overwrites strictly after.
__global__ __launch_bounds__(256, 4) void fused_kernel(
    const float* __restrict__ x, const int* __restrict__ ei,
    const float* __restrict__ Wself, const float* __restrict__ Wneigh,
    const float* __restrict__ bias,
    int* __restrict__ subcnt, int2* __restrict__ buf,
    float* __restrict__ s_norm, float* __restrict__ anf,
    float* __restrict__ out) {
    __shared__ float smraw[SM_FLOATS];
    const int tid = threadIdx.x;
    const int lane = tid & 63;
    const int wq = tid >> 6;
    const int bid = blockIdx.x;

    // ---- A: stage W into LDS (65-pad: 2-way bank alias only, free m136) ----
    float* Wl = smraw;
    #pragma unroll
    for (int v = 0; v < 4; ++v) {
        const int idx4 = v * 256 + tid;
        const int o = idx4 >> 4, k4 = (idx4 & 15) << 2;
        const float4 a = *(const float4*)&Wself[idx4 << 2];
        Wl[o * 65 + k4 + 0] = a.x; Wl[o * 65 + k4 + 1] = a.y;
        Wl[o * 65 + k4 + 2] = a.z; Wl[o * 65 + k4 + 3] = a.w;
        const float4 b = *(const float4*)&Wneigh[idx4 << 2];
        float* W2 = &Wl[64 * 65];
        W2[o * 65 + k4 + 0] = b.x; W2[o * 65 + k4 + 1] = b.y;
        W2[o * 65 + k4 + 2] = b.z; W2[o * 65 + k4 + 3] = b.w;
    }
    __syncthreads();

    // ---- B: edge binning, grid-stride (12 independent iters/wave -> ILP) ----
    // Self-edge: .set(w) overwrites (set-1.0 + eye) diag -> store w-1.
    // XCD-local sub-bins: cursor+tail lines stay in the owning XCD's L2.
    int xcc;  // HW_REG_XCC_ID = hwreg 20; 0-7 on MI355X (m09)
    asm volatile("s_getreg_b32 %0, hwreg(20, 0, 4)" : "=s"(xcc));
    xcc &= 7;
    const int j = lane & 7;
    const int gw = bid * 4 + wq;                  // 4096 waves
    for (int g = gw; g < N_EDGES / 8; g += NB * 4) {
        const int e = g * 8 + (lane >> 3);
        const int r = ei[e];
        const int c = ei[N_EDGES + e];

        const size_t rb = (size_t)r * 64 + j * 8;
        const size_t cb = (size_t)c * 64 + j * 8;
        const float4 xr0 = *(const float4*)&x[rb];
        const float4 xr1 = *(const float4*)&x[rb + 4];
        const float4 xc0 = *(const float4*)&x[cb];
        const float4 xc1 = *(const float4*)&x[cb + 4];

        float p = xr0.x*xc0.x + xr0.y*xc0.y + xr0.z*xc0.z + xr0.w*xc0.w
                + xr1.x*xc1.x + xr1.y*xc1.y + xr1.z*xc1.z + xr1.w*xc1.w;
        float nr = xr0.x*xr0.x + xr0.y*xr0.y + xr0.z*xr0.z + xr0.w*xr0.w
                 + xr1.x*xr1.x + xr1.y*xr1.y + xr1.z*xr1.z + xr1.w*xr1.w;
        float nc = xc0.x*xc0.x + xc0.y*xc0.y + xc0.z*xc0.z + xc0.w*xc0.w
                 + xc1.x*xc1.x + xc1.y*xc1.y + xc1.z*xc1.z + xc1.w*xc1.w;
        #pragma unroll
        for (int off = 1; off < 8; off <<= 1) {
            p  += __shfl_xor(p,  off);
            nr += __shfl_xor(nr, off);
            nc += __shfl_xor(nc, off);
        }

        const float cosv = p / (sqrtf(nr) * sqrtf(nc) + EPS);
        float w = fminf(fmaxf((cosv + 1.0f) * 0.5f, 0.1f), 0.9f);
        const float wv = (r == c) ? (w - 1.0f) : w;
        const int wbits = __float_as_int(wv);

        if (j < 2) {
            const int dest = j ? c : r;
            const int col  = j ? r : c;
            const int sub = (dest / NPB) * NXCD + xcc;
            const int s = atomicAdd(&subcnt[sub], 1);
            if (s < CAP_SUB)
                buf[(size_t)sub * CAP_SUB + s] = make_int2((dest << 14) | col, wbits);
        }
    }

    // ---- C: phase1, 3 nodes per wave (12 per block) ----
    {
        const int i0 = bid * NPB + wq * 3;
        const float* xr0 = &x[(size_t)(i0 + 0) * 64];
        const float* xr1 = &x[(size_t)(i0 + 1) * 64];
        const float* xr2 = &x[(size_t)(i0 + 2) * 64];
        const int o = lane;
        const float* Ws = &Wl[o * 65];
        const float* Wn = &Wl[64 * 65 + o * 65];

        float ys0 = 0.f, ys1 = 0.f, ys2 = 0.f;
        float yn0 = 0.f, yn1 = 0.f, yn2 = 0.f;
        #pragma unroll
        for (int t = 0; t < 16; ++t) {
            const int kb = 4 * t;
            const float4 a0 = *(const float4*)&xr0[kb];   // wave-uniform addr
            const float4 a1 = *(const float4*)&xr1[kb];
            const float4 a2 = *(const float4*)&xr2[kb];
            #pragma unroll
            for (int u = 0; u < 4; ++u) {
                const float ws = Ws[kb + u];
                const float wn = Wn[kb + u];
                const float e0 = u == 0 ? a0.x : u == 1 ? a0.y : u == 2 ? a0.z : a0.w;
                const float e1 = u == 0 ? a1.x : u == 1 ? a1.y : u == 2 ? a1.z : a1.w;
                const float e2 = u == 0 ? a2.x : u == 1 ? a2.y : u == 2 ? a2.z : a2.w;
                ys0 = fmaf(e0, ws, ys0); yn0 = fmaf(e0, wn, yn0);
                ys1 = fmaf(e1, ws, ys1); yn1 = fmaf(e1, wn, yn1);
                ys2 = fmaf(e2, ws, ys2); yn2 = fmaf(e2, wn, yn2);
            }
        }
        const float ns0 = sqrtf(wave_sum(ys0 * ys0));
        const float ns1 = sqrtf(wave_sum(ys1 * ys1));
        const float ns2 = sqrtf(wave_sum(ys2 * ys2));
        const float nn0 = sqrtf(wave_sum(yn0 * yn0));
        const float nn1 = sqrtf(wave_sum(yn1 * yn1));
        const float nn2 = sqrtf(wave_sum(yn2 * yn2));
        s_norm[(size_t)(i0 + 0) * 64 + o] = ys0 / (ns0 + EPS);
        s_norm[(size_t)(i0 + 1) * 64 + o] = ys1 / (ns1 + EPS);
        s_norm[(size_t)(i0 + 2) * 64 + o] = ys2 / (ns2 + EPS);
        anf[(size_t)(i0 + 0) * 64 + o] = yn0 / (nn0 + EPS);
        anf[(size_t)(i0 + 1) * 64 + o] = yn1 / (nn1 + EPS);
        anf[(size_t)(i0 + 2) * 64 + o] = yn2 / (nn2 + EPS);
    }

    // ---- D: grid-wide barrier (device-scope fence + all-blocks sync) ----
    __threadfence();
    cg::this_grid().sync();

    // ---- E: bin gather + projective chain (LDS reused: W is dead) ----
    int2* csr    = (int2*)smraw;                          // 12288 B
    unsigned* bm = (unsigned*)(smraw + NPB * NSLOT * 2);  // 18432 B
    int* cnt     = (int*)(smraw + NPB * NSLOT * 2 + NPB * BMW);

    for (int t = tid; t < NPB * BMW; t += 256) bm[t] = 0u;
    if (tid < NPB) cnt[tid] = 0;
    __syncthreads();

    for (int xc = 0; xc < NXCD; ++xc) {
        const int sub = bid * NXCD + xc;
        const int n = min(subcnt[sub], CAP_SUB);
        const int2* seg = &buf[(size_t)sub * CAP_SUB];
        for (int t = tid; t < n; t += 256) {
            const int2 rec = seg[t];
            const int dest = rec.x >> 14;
            const int col  = rec.x & 16383;
            const int l = dest - bid * NPB;
            const unsigned bit = 1u << (col & 31);
            const unsigned old = atomicOr(&bm[l * BMW + (col >> 5)], bit);
            if (!(old & bit)) {                  // exact .set dedup
                const int s = atomicAdd(&cnt[l], 1);
                if (s < NSLOT) csr[l * NSLOT + s] = make_int2(col, rec.y);
            }
        }
    }
    __syncthreads();

    const float bd = bias[lane];
    const float nb = sqrtf(wave_sum(bd * bd) + 1.0f);   // ||[bias,1]||, no eps
    const float bterm = 0.1f * (bd / nb);

    #pragma unroll 1
    for (int q = 0; q < 3; ++q) {
        const int l = wq * 3 + q;
        const int i = bid * NPB + l;
        const int d = min(cnt[l], NSLOT);

        float acc = anf[(size_t)i * 64 + lane];   // eye diagonal: 1.0*anf[i]
        #pragma unroll 4
        for (int k = 0; k < d; ++k) {
            const int2 ent = csr[l * NSLOT + k];  // wave-uniform broadcast
            acc = fmaf(__int_as_float(ent.y), anf[(size_t)ent.x * 64 + lane], acc);
        }
        float Sp = 0.f;
        if (lane < d)      Sp += __int_as_float(csr[l * NSLOT + lane].y);
        if (lane + 64 < d) Sp += __int_as_float(csr[l * NSLOT + lane + 64].y);
        const float S = 1.0f + wave_sum(Sp);

        const float v = acc / (S + EPS);
        const float nv = sqrtf(wave_sum(v * v));
        const float nf = v / (nv + EPS);          // neigh_trans feat

        const float s = s_norm[(size_t)i * 64 + lane];
        const float h = 0.5f * (s + nf);
        const float nh = sqrtf(wave_sum(h * h));
        const float hf = h / (nh + EPS);

        const float g = 0.9f * hf + bterm;
        const float ng = sqrtf(wave_sum(g * g));
        const float gf = g / (ng + EPS);

        const float rho = ng / (ng + EPS);
        out[(size_t)i * 64 + lane] = gf / (rho + EPS);
    }
}

// ---------------- fallback path (R8 kernels, proven) ----------------
__global__ __launch_bounds__(256) void phase1_kernel(
    const float* __restrict__ x, const float* __restrict__ Wself,
    const float* __restrict__ Wneigh,
    float* __restrict__ s_norm, float* __restrict__ anf) {
    __shared__ float Wl[2 * 64 * 65];
    const int tid = threadIdx.x;
    #pragma unroll
    for (int v = 0; v < 4; ++v) {
        const int idx4 = v * 256 + tid;
        const int o = idx4 >> 4, k4 = (idx4 & 15) << 2;
        const float4 a = *(const float4*)&Wself[idx4 << 2];
        Wl[o * 65 + k4 + 0] = a.x; Wl[o * 65 + k4 + 1] = a.y;
        Wl[o * 65 + k4 + 2] = a.z; Wl[o * 65 + k4 + 3] = a.w;
        const float4 b = *(const float4*)&Wneigh[idx4 << 2];
        float* W2 = &Wl[64 * 65];
        W2[o * 65 + k4 + 0] = b.x; W2[o * 65 + k4 + 1] = b.y;
        W2[o * 65 + k4 + 2] = b.z; W2[o * 65 + k4 + 3] = b.w;
    }
    __syncthreads();
    const int o = tid & 63;
    const int wq = tid >> 6;
    const int i0 = (blockIdx.x * 4 + wq) * 4;
    const float* xr0 = &x[(size_t)(i0 + 0) * 64];
    const float* xr1 = &x[(size_t)(i0 + 1) * 64];
    const float* xr2 = &x[(size_t)(i0 + 2) * 64];
    const float* xr3 = &x[(size_t)(i0 + 3) * 64];
    const float* Ws = &Wl[o * 65];
    const float* Wn = &Wl[64 * 65 + o * 65];
    float ys0 = 0.f, ys1 = 0.f, ys2 = 0.f, ys3 = 0.f;
    float yn0 = 0.f, yn1 = 0.f, yn2 = 0.f, yn3 = 0.f;
    #pragma unroll
    for (int t = 0; t < 16; ++t) {
        const int kb = 4 * t;
        const float4 a0 = *(const float4*)&xr0[kb];
        const float4 a1 = *(const float4*)&xr1[kb];
        const float4 a2 = *(const float4*)&xr2[kb];
        const float4 a3 = *(const float4*)&xr3[kb];
        #pragma unroll
        for (int u = 0; u < 4; ++u) {
            const float ws = Ws[kb + u];
            const float wn = Wn[kb + u];
            const float e0 = u == 0 ? a0.x : u == 1 ? a0.y : u == 2 ? a0.z : a0.w;
            const float e1 = u == 0 ? a1.x : u == 1 ? a1.y : u == 2 ? a1.z : a1.w;
            const float e2 = u == 0 ? a2.x : u == 1 ? a2.y : u == 2 ? a2.z : a2.w;
            const float e3 = u == 0 ? a3.x : u == 1 ? a3.y : u == 2 ? a3.z : a3.w;
            ys0 = fmaf(e0, ws, ys0); yn0 = fmaf(e0, wn, yn0);
            ys1 = fmaf(e1, ws, ys1); yn1 = fmaf(e1, wn, yn1);
            ys2 = fmaf(e2, ws, ys2); yn2 = fmaf(e2, wn, yn2);
            ys3 = fmaf(e3, ws, ys3); yn3 = fmaf(e3, wn, yn3);
        }
    }
    const float ns0 = sqrtf(wave_sum(ys0 * ys0));
    const float ns1 = sqrtf(wave_sum(ys1 * ys1));
    const float ns2 = sqrtf(wave_sum(ys2 * ys2));
    const float ns3 = sqrtf(wave_sum(ys3 * ys3));
    const float nn0 = sqrtf(wave_sum(yn0 * yn0));
    const float nn1 = sqrtf(wave_sum(yn1 * yn1));
    const float nn2 = sqrtf(wave_sum(yn2 * yn2));
    const float nn3 = sqrtf(wave_sum(yn3 * yn3));
    s_norm[(size_t)(i0 + 0) * 64 + o] = ys0 / (ns0 + EPS);
    s_norm[(size_t)(i0 + 1) * 64 + o] = ys1 / (ns1 + EPS);
    s_norm[(size_t)(i0 + 2) * 64 + o] = ys2 / (ns2 + EPS);
    s_norm[(size_t)(i0 + 3) * 64 + o] = ys3 / (ns3 + EPS);
    anf[(size_t)(i0 + 0) * 64 + o] = yn0 / (nn0 + EPS);
    anf[(size_t)(i0 + 1) * 64 + o] = yn1 / (nn1 + EPS);
    anf[(size_t)(i0 + 2) * 64 + o] = yn2 / (nn2 + EPS);
    anf[(size_t)(i0 + 3) * 64 + o] = yn3 / (nn3 + EPS);
}

__global__ __launch_bounds__(256) void edge_bin_kernel(
    const float* __restrict__ x, const int* __restrict__ ei,
    int* __restrict__ subcnt, int2* __restrict__ buf) {
    const int lane = threadIdx.x & 63;
    const int j = lane & 7;
    const int wave = blockIdx.x * 4 + (threadIdx.x >> 6);
    const int e = wave * 8 + (lane >> 3);
    const int r = ei[e];
    const int c = ei[N_EDGES + e];
    const size_t rb = (size_t)r * 64 + j * 8;
    const size_t cb = (size_t)c * 64 + j * 8;
    const float4 xr0 = *(const float4*)&x[rb];
    const float4 xr1 = *(const float4*)&x[rb + 4];
    const float4 xc0 = *(const float4*)&x[cb];
    const float4 xc1 = *(const float4*)&x[cb + 4];
    float p = xr0.x*xc0.x + xr0.y*xc0.y + xr0.z*xc0.z + xr0.w*xc0.w
            + xr1.x*xc1.x + xr1.y*xc1.y + xr1.z*xc1.z + xr1.w*xc1.w;
    float nr = xr0.x*xr0.x + xr0.y*xr0.y + xr0.z*xr0.z + xr0.w*xr0.w
             + xr1.x*xr1.x + xr1.y*xr1.y + xr1.z*xr1.z + xr1.w*xr1.w;
    float nc = xc0.x*xc0.x + xc0.y*xc0.y + xc0.z*xc0.z + xc0.w*xc0.w
             + xc1.x*xc1.x + xc1.y*xc1.y + xc1.z*xc1.z + xc1.w*xc1.w;
    #pragma unroll
    for (int off = 1; off < 8; off <<= 1) {
        p  += __shfl_xor(p,  off);
        nr += __shfl_xor(nr, off);
        nc += __shfl_xor(nc, off);
    }
    const float cosv = p / (sqrtf(nr) * sqrtf(nc) + EPS);
    float w = fminf(fmaxf((cosv + 1.0f) * 0.5f, 0.1f), 0.9f);
    const float wv = (r == c) ? (w - 1.0f) : w;
    const int wbits = __float_as_int(wv);
    int xcc;
    asm volatile("s_getreg_b32 %0, hwreg(20, 0, 4)" : "=s"(xcc));
    xcc &= 7;
    if (j < 2) {
        const int dest = j ? c : r;
        const int col  = j ? r : c;
        const int sub = (dest / NPB) * NXCD + xcc;
        const int s = atomicAdd(&subcnt[sub], 1);
        if (s < CAP_SUB)
            buf[(size_t)sub * CAP_SUB + s] = make_int2((dest << 14) | col, wbits);
    }
}

__global__ __launch_bounds__(256) void bin_gather_kernel(
    const int* __restrict__ subcnt, const int2* __restrict__ buf,
    const float* __restrict__ anf, const float* __restrict__ s_norm,
    const float* __restrict__ bias, float* __restrict__ out) {
    __shared__ int2 csr[NPB][NSLOT];
    __shared__ unsigned bm[NPB * BMW];
    __shared__ int cnt[NPB];
    const int tid = threadIdx.x;
    const int lane = tid & 63;
    const int w4 = tid >> 6;
    const int bin = blockIdx.x;
    const int node0 = bin * NPB;
    for (int t = tid; t < NPB * BMW; t += 256) bm[t] = 0u;
    if (tid < NPB) cnt[tid] = 0;
    __syncthreads();
    for (int xc = 0; xc < NXCD; ++xc) {
        const int sub = bin * NXCD + xc;
        const int n = min(subcnt[sub], CAP_SUB);
        const int2* seg = &buf[(size_t)sub * CAP_SUB];
        for (int t = tid; t < n; t += 256) {
            const int2 rec = seg[t];
            const int dest = rec.x >> 14;
            const int col  = rec.x & 16383;
            const int l = dest - node0;
            const unsigned bit = 1u << (col & 31);
            const unsigned old = atomicOr(&bm[l * BMW + (col >> 5)], bit);
            if (!(old & bit)) {
                const int s = atomicAdd(&cnt[l], 1);
                if (s < NSLOT) csr[l][s] = make_int2(col, rec.y);
            }
        }
    }
    __syncthreads();
    const float bd = bias[lane];
    const float nb = sqrtf(wave_sum(bd * bd) + 1.0f);
    const float bterm = 0.1f * (bd / nb);
    #pragma unroll 1
    for (int q = 0; q < 3; ++q) {
        const int l = w4 * 3 + q;
        const int i = node0 + l;
        const int d = min(cnt[l], NSLOT);
        float acc = anf[(size_t)i * 64 + lane];
        #pragma unroll 4
        for (int k = 0; k < d; ++k) {
            const int2 ent = csr[l][k];
            acc = fmaf(__int_as_float(ent.y), anf[(size_t)ent.x * 64 + lane], acc);
        }
        float Sp = 0.f;
        if (lane < d)      Sp += __int_as_float(csr[l][lane].y);
        if (lane + 64 < d) Sp += __int_as_float(csr[l][lane + 64].y);
        const float S = 1.0f + wave_sum(Sp);
        const float v = acc / (S + EPS);
        const float nv = sqrtf(wave_sum(v * v));
        const float nf = v / (nv + EPS);
        const float s = s_norm[(size_t)i * 64 + lane];
        const float h = 0.5f * (s + nf);
        const float nh = sqrtf(wave_sum(h * h));
        const float hf = h / (nh + EPS);
        const float g = 0.9f * hf + bterm;
        const float ng = sqrtf(wave_sum(g * g));
        const float gf = g / (ng + EPS);
        const float rho = ng / (ng + EPS);
        out[(size_t)i * 64 + lane] = gf / (rho + EPS);
    }
}

extern "C" void kernel_launch(void* const* d_in, const int* in_sizes, int n_in,
                              void* d_out, int out_size, void* d_ws, size_t ws_size,
                              hipStream_t stream) {
    const float* x      = (const float*)d_in[0];
    const int*   ei     = (const int*)  d_in[1];
    const float* Wself  = (const float*)d_in[2];
    const float* Wneigh = (const float*)d_in[3];
    const float* bias   = (const float*)d_in[4];
    float* out = (float*)d_out;

    // workspace carve-up (~22.9 MB)
    const size_t ROW_BYTES = (size_t)N_NODES * 64 * sizeof(float);
    char* ws = (char*)d_ws;
    int*  subcnt = (int*)ws;    ws += (size_t)NSUB * sizeof(int);            // 32 KB
    int2* buf    = (int2*)ws;   ws += (size_t)NSUB * CAP_SUB * sizeof(int2); // 16.8 MB
    float* s_norm = (float*)ws; ws += ROW_BYTES;                             // 3 MB
    float* anf    = (float*)ws; ws += ROW_BYTES;                             // 3 MB

    hipMemsetAsync(subcnt, 0, (size_t)NSUB * sizeof(int), stream);

    // cooperative path requires all 1024 blocks co-resident (4/CU)
    int maxb = 0;
    hipError_t st = hipOccupancyMaxActiveBlocksPerMultiprocessor(
        &maxb, reinterpret_cast<const void*>(fused_kernel), 256, 0);

    if (st == hipSuccess && maxb >= 4) {
        void* args[] = {(void*)&x, (void*)&ei, (void*)&Wself, (void*)&Wneigh,
                        (void*)&bias, (void*)&subcnt, (void*)&buf,
                        (void*)&s_norm, (void*)&anf, (void*)&out};
        hipLaunchCooperativeKernel(reinterpret_cast<const void*>(fused_kernel),
                                   dim3(NB), dim3(256), args, 0, stream);
    } else {
        edge_bin_kernel<<<N_EDGES / 8 / 4, 256, 0, stream>>>(x, ei, subcnt, buf);
        phase1_kernel<<<768, 256, 0, stream>>>(x, Wself, Wneigh, s_norm, anf);
        bin_gather_kernel<<<NB, 256, 0, stream>>>(subcnt, buf, anf, s_norm,
                                                  bias, out);
    }
}